// Round 16
// baseline (156.392 us; speedup 1.0000x reference)
//
#include <hip/hip_runtime.h>
#include <hip/hip_cooperative_groups.h>
#include <math.h>

namespace cg = cooperative_groups;

#define N_NODES 10000
#define BB 8192
#define KK 10
#define D 172
#define HIDD 80

typedef _Float16 f16;
typedef f16 f16x8 __attribute__((ext_vector_type(8)));
typedef f16 f16x4 __attribute__((ext_vector_type(4)));
typedef float f32x4 __attribute__((ext_vector_type(4)));

// ---------------- prep (cooperative): conv + FEAT + init, scatter, compact ----------------
#define CR0 135168              // Wc 192*704
#define CR1 (CR0 + 104448)      // W1 192*544
#define CR2 (CR1 + 67584)       // W2 192*352
#define CR3 (CR2 + 15360)       // Wm1 80*192
#define CR4 (CR3 + 192)         // bcomb/embc
#define CR5 (CR4 + 220000)      // FEAT 10000*22
#define CR6 (CR5 + 10001)       // last_idx init + cnt

__global__ __launch_bounds__(768) void prep_coop(
    const float* __restrict__ Wih, const float* __restrict__ Whh,
    const float* __restrict__ lin1_w, const float* __restrict__ lin2_w,
    const float* __restrict__ w1,
    const float* __restrict__ bih, const float* __restrict__ bhh,
    const float* __restrict__ lin2_b, const float* __restrict__ tb,
    const float* __restrict__ node_mem, const float* __restrict__ tnf,
    const int* __restrict__ sources,
    f16* __restrict__ Wc, f16* __restrict__ W1, f16* __restrict__ W2,
    f16* __restrict__ Wm1, float* __restrict__ bcomb, float* __restrict__ embc,
    f16* __restrict__ FEAT, int* __restrict__ last_idx,
    int* __restrict__ nid, int* __restrict__ li_arr, int* __restrict__ cnt)
{
    cg::grid_group grid = cg::this_grid();
    const int t = threadIdx.x;
    // phase 0: weight conversion + FEAT baseline + last_idx/cnt init
    for (int idx = blockIdx.x * 768 + t; idx < CR6; idx += 256 * 768) {
        if (idx < CR0) {
            int n = idx / 704, k = idx % 704, seg = k / 176, kk = k % 176;
            float v = 0.f;
            if (n < D && kk < D) {
                v = Wih[n * 688 + seg * D + kk];
                if (seg == 0) v += Whh[n * D + kk];
            }
            Wc[idx] = (f16)v;
        } else if (idx < CR1) {
            int i = idx - CR0;
            int n = i / 544, k = i % 544, seg = k / 176, kk = k % 176;
            float v = 0.f;
            if (n < D && seg < 3 && kk < D) v = lin1_w[n * 516 + seg * D + kk];
            W1[i] = (f16)v;
        } else if (idx < CR2) {
            int i = idx - CR1;
            int n = i / 352, k = i % 352, seg = k / 176, kk = k % 176;
            float v = 0.f;
            if (n < D && kk < D) v = lin2_w[n * 516 + seg * D + kk];
            W2[i] = (f16)v;
        } else if (idx < CR3) {
            int i = idx - CR2;
            int n = i / 192, k = i % 192;
            Wm1[i] = (f16)((k < D) ? w1[n * D + k] : 0.f);
        } else if (idx < CR4) {
            int i = idx - CR3;
            if (i < D) {
                bcomb[i] = bih[i] + bhh[i];
                float acc = lin2_b[i];
                for (int j = 0; j < D; ++j) acc += lin2_w[i * 516 + 344 + j] * __cosf(tb[j]);
                embc[i] = acc;
            }
        } else if (idx < CR5) {
            int i = idx - CR4;
            int n = i / 22, k0 = (i % 22) * 8;
            f16x8 o;
            #pragma unroll
            for (int j = 0; j < 8; ++j) {
                int kk = k0 + j;
                float v = (kk < D) ? node_mem[(size_t)n * D + kk] + tnf[(size_t)n * D + kk] : 0.f;
                o[j] = (f16)v;
            }
            *(f16x8*)(FEAT + (size_t)n * 176 + k0) = o;
        } else {
            int i = idx - CR5;
            if (i < N_NODES) last_idx[i] = -1;
            else *cnt = 0;
        }
    }
    grid.sync();
    // phase 1: scatter last message per source node
    for (int b = blockIdx.x * 768 + t; b < BB; b += 256 * 768)
        atomicMax(&last_idx[sources[b]], b);
    grid.sync();
    // phase 2: compact updated nodes
    for (int n = blockIdx.x * 768 + t; n < N_NODES; n += 256 * 768) {
        int li = last_idx[n];
        if (li >= 0) { int p = atomicAdd(cnt, 1); nid[p] = n; li_arr[p] = li; }
    }
}

// ---------------- GEMM 1 fused (compacted rows): BM=16, 768 thr (11 MFMA waves x 16 cols) ----------------
#define LDA_R 712   // 704 + 8 pad halfs

__global__ __launch_bounds__(768) void gemm_rnn_fused(
    const f16* __restrict__ Wc, const float* __restrict__ bcomb,
    const int* __restrict__ nid, const int* __restrict__ li_arr, const int* __restrict__ cnt,
    const int* __restrict__ destinations, const int* __restrict__ edge_idxs,
    const float* __restrict__ timestamps, const float* __restrict__ last_updated,
    const float* __restrict__ node_mem, const float* __restrict__ edge_features,
    const float* __restrict__ tw, const float* __restrict__ tb,
    const float* __restrict__ tnf, f16* __restrict__ FEAT)
{
    const int c = *cnt;
    const int R0 = blockIdx.x * 16;
    if (R0 >= c) return;
    __shared__ f16 As[16 * LDA_R];
    __shared__ int s_n[16], s_dst[16], s_ei[16];
    __shared__ float s_dt[16];
    const int t = threadIdx.x;
    if (t < 16) {
        int i = R0 + t; if (i > c - 1) i = c - 1;
        int n = nid[i], li = li_arr[i];
        s_n[t] = n; s_dst[t] = destinations[li]; s_ei[t] = edge_idxs[li];
        s_dt[t] = timestamps[li] - last_updated[n];
    }
    __syncthreads();
    for (int idx = t; idx < 16 * 88; idx += 768) {
        int row = idx / 88, sub = idx - row * 88;
        int seg = sub / 22, cpos = sub - seg * 22, k0 = cpos * 8;
        f16x8 o;
        if (seg < 3) {
            int n = (seg == 0) ? s_n[row] : (seg == 1) ? s_dst[row] : s_ei[row];
            const float* src = ((seg < 2) ? node_mem : edge_features) + (size_t)n * D + k0;
            float4 lo = *(const float4*)src;
            float4 hi = (cpos < 21) ? *(const float4*)(src + 4) : make_float4(0.f, 0.f, 0.f, 0.f);
            o[0] = (f16)lo.x; o[1] = (f16)lo.y; o[2] = (f16)lo.z; o[3] = (f16)lo.w;
            o[4] = (f16)hi.x; o[5] = (f16)hi.y; o[6] = (f16)hi.z; o[7] = (f16)hi.w;
        } else {
            float dt = s_dt[row];
            #pragma unroll
            for (int j = 0; j < 8; ++j) {
                int kk = k0 + j;
                o[j] = (f16)((kk < D) ? __cosf(dt * tw[kk] + tb[kk]) : 0.f);
            }
        }
        *(f16x8*)(As + row * LDA_R + seg * 176 + k0) = o;
    }
    __syncthreads();
    const int w = t >> 6, l = t & 63;
    if (w >= 11) return;
    const int lane16 = l & 15, koff = (l >> 4) * 8;
    const int C0 = w * 16;
    const f16* Al = As + lane16 * LDA_R + koff;
    const f16* Bp = Wc + (size_t)(C0 + lane16) * 704 + koff;
    f32x4 acc = {};
    #pragma unroll 2
    for (int s = 0; s < 22; ++s) {
        f16x8 a = *(const f16x8*)(Al + s * 32);
        f16x8 b = *(const f16x8*)(Bp + s * 32);
        acc = __builtin_amdgcn_mfma_f32_16x16x32_f16(a, b, acc, 0, 0, 0);
    }
    const int col = C0 + lane16;
    const int rloc = (l >> 4) * 4;
    if (col < D) {
        const float bc = bcomb[col];
        #pragma unroll
        for (int reg = 0; reg < 4; ++reg) {
            int rl = rloc + reg;
            int r = R0 + rl;
            if (r >= c) continue;
            int n = s_n[rl];
            FEAT[(size_t)n * 176 + col] = (f16)(tanhf(acc[reg] + bc) + tnf[(size_t)n * D + col]);
        }
    }
}

// ---------------- embed_fused (BM=16): stage G + srcfeat -> lin1 -> lin2 -> mlp -> out ----------------
#define LDA_1 552   // G leading dim: 544 + 8
#define LDA_2 360   // Acat leading dim: 352 + 8
#define LDE  200    // Emb leading dim: 192 + 8

__global__ __launch_bounds__(768) void embed_fused(
    const f16* __restrict__ W1, const float* __restrict__ lin1_b,
    const f16* __restrict__ W2, const float* __restrict__ embc,
    const f16* __restrict__ Wm1, const float* __restrict__ b1,
    const float* __restrict__ w2, const float* __restrict__ b2,
    const float* __restrict__ w3, const float* __restrict__ b3,
    const f16* __restrict__ FEAT, const float* __restrict__ edge_features,
    const float* __restrict__ timestamps, const float* __restrict__ nbr_edge_times,
    const int* __restrict__ neighbors, const int* __restrict__ nbr_edge_idxs,
    const int* __restrict__ sources,
    const float* __restrict__ tw, const float* __restrict__ tb,
    float* __restrict__ out)
{
    __shared__ f16 As[16 * LDA_1];      // G staging; reused as Emb after lin1/lin2
    __shared__ f16 Acat[16 * LDA_2];    // [H1(0:176) | srcfeat(176:352)]
    __shared__ float sH[16][84];
    __shared__ float s_w2[10 * HIDD];
    __shared__ float s_b2[10], s_w3[10], s_b3;
    __shared__ int s_nbr[160], s_nei[160], s_src[16];
    __shared__ float s_net[160], s_ts[16];
    const int t = threadIdx.x;
    const int R0 = blockIdx.x * 16;
    for (int i = t; i < 10 * HIDD; i += 768) s_w2[i] = w2[i];
    if (t < 10) { s_b2[t] = b2[t]; s_w3[t] = w3[t]; }
    if (t == 10) s_b3 = b3[0];
    if (t >= 64 && t < 224) {
        int u = t - 64;
        s_nbr[u] = neighbors[R0 * KK + u];
    } else if (t >= 224 && t < 384) {
        int u = t - 224;
        s_nei[u] = nbr_edge_idxs[R0 * KK + u];
        s_net[u] = nbr_edge_times[R0 * KK + u];
    } else if (t >= 384 && t < 400) {
        s_ts[t - 384] = timestamps[R0 + t - 384];
    } else if (t >= 400 && t < 416) {
        s_src[t - 400] = sources[R0 + t - 400];
    }
    __syncthreads();
    for (int idx = t; idx < 16 * 90 + 16 * 22; idx += 768) {
        if (idx < 16 * 90) {
            int row = idx / 90, c = idx - row * 90;
            if (c < 22) {
                int k0 = c * 8;
                f16x8 v[KK];
                #pragma unroll
                for (int k = 0; k < KK; ++k)
                    v[k] = *(const f16x8*)(FEAT + (size_t)s_nbr[row * KK + k] * 176 + k0);
                float a[8] = {};
                #pragma unroll
                for (int k = 0; k < KK; ++k) {
                    #pragma unroll
                    for (int j = 0; j < 8; ++j) a[j] += (float)v[k][j];
                }
                f16x8 o;
                #pragma unroll
                for (int j = 0; j < 8; ++j) o[j] = (f16)a[j];
                *(f16x8*)(As + row * LDA_1 + k0) = o;
            } else if (c < 44) {
                int k0 = (c - 22) * 8;
                float ts = s_ts[row];
                f16x8 o;
                #pragma unroll
                for (int j = 0; j < 8; ++j) {
                    int kk = k0 + j;
                    float a = 0.f;
                    if (kk < D) {
                        float w = tw[kk], bb = tb[kk];
                        #pragma unroll
                        for (int k = 0; k < KK; ++k) a += __cosf((ts - s_net[row * KK + k]) * w + bb);
                    }
                    o[j] = (f16)a;
                }
                *(f16x8*)(As + row * LDA_1 + 176 + k0) = o;
            } else if (c < 88) {
                int cc = c - 44;
                f16x4 o;
                if (cc == 43) {
                    o[0] = o[1] = o[2] = o[3] = (f16)0.f;
                } else {
                    float4 e[KK];
                    #pragma unroll
                    for (int k = 0; k < KK; ++k)
                        e[k] = *(const float4*)(edge_features + (size_t)s_nei[row * KK + k] * D + cc * 4);
                    float a0 = 0.f, a1 = 0.f, a2 = 0.f, a3 = 0.f;
                    #pragma unroll
                    for (int k = 0; k < KK; ++k) { a0 += e[k].x; a1 += e[k].y; a2 += e[k].z; a3 += e[k].w; }
                    o[0] = (f16)a0; o[1] = (f16)a1; o[2] = (f16)a2; o[3] = (f16)a3;
                }
                *(f16x4*)(As + row * LDA_1 + 352 + cc * 4) = o;
            } else {
                f16x8 z = {};
                *(f16x8*)(As + row * LDA_1 + 528 + (c - 88) * 8) = z;
            }
        } else {
            int j = idx - 16 * 90;
            int row = j / 22, cc = j - row * 22;
            *(f16x8*)(Acat + row * LDA_2 + 176 + cc * 8) =
                *(const f16x8*)(FEAT + (size_t)s_src[row] * 176 + cc * 8);
        }
    }
    __syncthreads();
    const int w = t >> 6, l = t & 63;
    const int lane16 = l & 15, koff = (l >> 4) * 8;
    const int rloc = (l >> 4) * 4;
    const int C0 = w * 16;
    if (w < 11) {   // lin1 -> Acat[:,0:176)
        const f16* Al = As + lane16 * LDA_1 + koff;
        const f16* Bp = W1 + (size_t)(C0 + lane16) * 544 + koff;
        f32x4 acc = {};
        #pragma unroll 2
        for (int s = 0; s < 17; ++s) {
            f16x8 a = *(const f16x8*)(Al + s * 32);
            f16x8 b = *(const f16x8*)(Bp + s * 32);
            acc = __builtin_amdgcn_mfma_f32_16x16x32_f16(a, b, acc, 0, 0, 0);
        }
        const int col = C0 + lane16;
        if (col < 176) {
            const float bb = (col < D) ? 10.0f * lin1_b[col] : 0.f;
            #pragma unroll
            for (int reg = 0; reg < 4; ++reg) {
                int r = rloc + reg;
                Acat[r * LDA_2 + col] = (col < D) ? (f16)fmaxf(acc[reg] + bb, 0.f) : (f16)0.f;
            }
        }
    }
    __syncthreads();
    f16* Emb = As;   // reuse
    if (w < 11) {   // lin2 -> Emb
        const f16* Al = Acat + lane16 * LDA_2 + koff;
        const f16* Bp = W2 + (size_t)(C0 + lane16) * 352 + koff;
        f32x4 acc = {};
        #pragma unroll 2
        for (int s = 0; s < 11; ++s) {
            f16x8 a = *(const f16x8*)(Al + s * 32);
            f16x8 b = *(const f16x8*)(Bp + s * 32);
            acc = __builtin_amdgcn_mfma_f32_16x16x32_f16(a, b, acc, 0, 0, 0);
        }
        const int col = C0 + lane16;
        const float ec = (col < D) ? embc[col] : 0.f;
        #pragma unroll
        for (int reg = 0; reg < 4; ++reg) {
            int r = rloc + reg;
            Emb[r * LDE + col] = (col < D) ? (f16)(acc[reg] + ec) : (f16)0.f;
        }
    }
    __syncthreads();
    if (w < 5) {  // mlp layer 1 -> sH
        const int Cm = w * 16;
        const f16* Bp = Wm1 + (size_t)(Cm + lane16) * 192 + koff;
        const f16* Al = Emb + (lane16) * LDE + koff;
        f32x4 acc = {};
        #pragma unroll
        for (int s = 0; s < 6; ++s) {
            f16x8 a = *(const f16x8*)(Al + s * 32);
            f16x8 b = *(const f16x8*)(Bp + s * 32);
            acc = __builtin_amdgcn_mfma_f32_16x16x32_f16(a, b, acc, 0, 0, 0);
        }
        const int col = Cm + lane16;
        #pragma unroll
        for (int reg = 0; reg < 4; ++reg)
            sH[rloc + reg][col] = fmaxf(acc[reg] + b1[col], 0.f);
    }
    __syncthreads();
    if (t < 16) {
        float h2[10];
        #pragma unroll
        for (int j = 0; j < 10; ++j) h2[j] = s_b2[j];
        for (int f = 0; f < HIDD; ++f) {
            float hv = sH[t][f];
            #pragma unroll
            for (int j = 0; j < 10; ++j) h2[j] = fmaf(hv, s_w2[j * HIDD + f], h2[j]);
        }
        float logit = s_b3;
        #pragma unroll
        for (int j = 0; j < 10; ++j) logit += fmaxf(h2[j], 0.f) * s_w3[j];
        out[R0 + t] = 1.f / (1.f + expf(-logit));
    }
}

// ---------------- host ----------------

extern "C" void kernel_launch(void* const* d_in, const int* in_sizes, int n_in,
                              void* d_out, int out_size, void* d_ws, size_t ws_size,
                              hipStream_t stream) {
    const float* timestamps     = (const float*)d_in[0];
    const float* edge_features  = (const float*)d_in[1];
    const float* tnf            = (const float*)d_in[2];
    const float* node_mem       = (const float*)d_in[3];
    const float* last_updated   = (const float*)d_in[4];
    const float* nbr_edge_times = (const float*)d_in[5];
    const float* time_w         = (const float*)d_in[6];
    const float* time_b         = (const float*)d_in[7];
    const float* Wih            = (const float*)d_in[8];
    const float* Whh            = (const float*)d_in[9];
    const float* bih            = (const float*)d_in[10];
    const float* bhh            = (const float*)d_in[11];
    const float* lin1_w         = (const float*)d_in[12];
    const float* lin1_b         = (const float*)d_in[13];
    const float* lin2_w         = (const float*)d_in[14];
    const float* lin2_b         = (const float*)d_in[15];
    const float* w1             = (const float*)d_in[16];
    const float* b1             = (const float*)d_in[17];
    const float* w2             = (const float*)d_in[18];
    const float* b2             = (const float*)d_in[19];
    const float* w3             = (const float*)d_in[20];
    const float* b3             = (const float*)d_in[21];
    const int* sources          = (const int*)d_in[22];
    const int* destinations     = (const int*)d_in[23];
    const int* edge_idxs        = (const int*)d_in[24];
    const int* neighbors        = (const int*)d_in[25];
    const int* nbr_edge_idxs    = (const int*)d_in[26];
    float* out = (float*)d_out;

    char* p = (char*)d_ws;
    auto bump = [&p](size_t bytes) { char* r = p; p += (bytes + 255) & ~(size_t)255; return r; };
    int* last_idx = (int*)bump(N_NODES * 4);
    int* nid      = (int*)bump(N_NODES * 4);
    int* li_arr   = (int*)bump(N_NODES * 4);
    int* cnt      = (int*)bump(256);
    f16* Wc16     = (f16*)bump((size_t)192 * 704 * 2);
    f16* W1_16    = (f16*)bump((size_t)192 * 544 * 2);
    f16* W2_16    = (f16*)bump((size_t)192 * 352 * 2);
    f16* Wm1_16   = (f16*)bump((size_t)80 * 192 * 2);
    float* bcomb  = (float*)bump(D * 4);
    float* embc   = (float*)bump(D * 4);
    f16* FEAT16   = (f16*)bump((size_t)N_NODES * 176 * 2);

    void* args[] = {
        (void*)&Wih, (void*)&Whh, (void*)&lin1_w, (void*)&lin2_w, (void*)&w1,
        (void*)&bih, (void*)&bhh, (void*)&lin2_b, (void*)&time_b,
        (void*)&node_mem, (void*)&tnf, (void*)&sources,
        (void*)&Wc16, (void*)&W1_16, (void*)&W2_16, (void*)&Wm1_16,
        (void*)&bcomb, (void*)&embc, (void*)&FEAT16, (void*)&last_idx,
        (void*)&nid, (void*)&li_arr, (void*)&cnt
    };
    hipLaunchCooperativeKernel((const void*)prep_coop, dim3(256), dim3(768), args, 0, stream);

    hipLaunchKernelGGL(gemm_rnn_fused, dim3((N_NODES + 15) / 16), dim3(768), 0, stream,
                       Wc16, bcomb, nid, li_arr, cnt, destinations, edge_idxs,
                       timestamps, last_updated, node_mem, edge_features,
                       time_w, time_b, tnf, FEAT16);

    hipLaunchKernelGGL(embed_fused, dim3(BB / 16), dim3(768), 0, stream,
                       W1_16, lin1_b, W2_16, embc, Wm1_16, b1, w2, b2, w3, b3,
                       FEAT16, edge_features, timestamps, nbr_edge_times,
                       neighbors, nbr_edge_idxs, sources, time_w, time_b, out);
}

// Round 17
// 108.384 us; speedup vs baseline: 1.4429x; 1.4429x over previous
//
#include <hip/hip_runtime.h>
#include <math.h>

#define N_NODES 10000
#define BB 8192
#define KK 10
#define D 172
#define HIDD 80

typedef _Float16 f16;
typedef f16 f16x8 __attribute__((ext_vector_type(8)));
typedef f16 f16x4 __attribute__((ext_vector_type(4)));
typedef float f32x4 __attribute__((ext_vector_type(4)));

// ---------------- conv_weights: flat 1D ranges (weights, consts, FEAT, init) ----------------
#define CR0 135168              // Wc 192*704
#define CR1 (CR0 + 104448)      // W1 192*544
#define CR2 (CR1 + 67584)       // W2 192*352
#define CR3 (CR2 + 15360)       // Wm1 80*192
#define CR4 (CR3 + 192)         // bcomb/embc
#define CR5 (CR4 + 220000)      // FEAT 10000*22
#define CR6 (CR5 + 10002)       // last_idx init + cnt + done

__global__ __launch_bounds__(256) void conv_weights(
    const float* __restrict__ Wih, const float* __restrict__ Whh,
    const float* __restrict__ lin1_w, const float* __restrict__ lin2_w,
    const float* __restrict__ w1,
    const float* __restrict__ bih, const float* __restrict__ bhh,
    const float* __restrict__ lin2_b, const float* __restrict__ tb,
    const float* __restrict__ node_mem, const float* __restrict__ tnf,
    f16* __restrict__ Wc, f16* __restrict__ W1, f16* __restrict__ W2,
    f16* __restrict__ Wm1, float* __restrict__ bcomb, float* __restrict__ embc,
    f16* __restrict__ FEAT, int* __restrict__ last_idx,
    int* __restrict__ cnt, int* __restrict__ done)
{
    const int idx = blockIdx.x * 256 + threadIdx.x;
    if (idx < CR0) {
        int n = idx / 704, k = idx % 704, seg = k / 176, kk = k % 176;
        float v = 0.f;
        if (n < D && kk < D) {
            v = Wih[n * 688 + seg * D + kk];
            if (seg == 0) v += Whh[n * D + kk];
        }
        Wc[idx] = (f16)v;
    } else if (idx < CR1) {
        int i = idx - CR0;
        int n = i / 544, k = i % 544, seg = k / 176, kk = k % 176;
        float v = 0.f;
        if (n < D && seg < 3 && kk < D) v = lin1_w[n * 516 + seg * D + kk];
        W1[i] = (f16)v;
    } else if (idx < CR2) {
        int i = idx - CR1;
        int n = i / 352, k = i % 352, seg = k / 176, kk = k % 176;
        float v = 0.f;
        if (n < D && kk < D) v = lin2_w[n * 516 + seg * D + kk];
        W2[i] = (f16)v;
    } else if (idx < CR3) {
        int i = idx - CR2;
        int n = i / 192, k = i % 192;
        Wm1[i] = (f16)((k < D) ? w1[n * D + k] : 0.f);
    } else if (idx < CR4) {
        int i = idx - CR3;
        if (i < D) {
            bcomb[i] = bih[i] + bhh[i];
            float acc = lin2_b[i];
            for (int j = 0; j < D; ++j) acc += lin2_w[i * 516 + 344 + j] * __cosf(tb[j]);
            embc[i] = acc;
        }
    } else if (idx < CR5) {
        int i = idx - CR4;
        int n = i / 22, k0 = (i % 22) * 8;
        f16x8 o;
        #pragma unroll
        for (int j = 0; j < 8; ++j) {
            int kk = k0 + j;
            float v = (kk < D) ? node_mem[(size_t)n * D + kk] + tnf[(size_t)n * D + kk] : 0.f;
            o[j] = (f16)v;
        }
        *(f16x8*)(FEAT + (size_t)n * 176 + k0) = o;
    } else if (idx < CR6) {
        int i = idx - CR5;
        if (i < N_NODES) last_idx[i] = -1;
        else if (i == N_NODES) *cnt = 0;
        else *done = 0;
    }
}

// ---------------- scatter + compact fused (done-counter, last block compacts) ----------------
__global__ __launch_bounds__(256) void scatter_compact(
    const int* __restrict__ sources, int* __restrict__ last_idx,
    int* __restrict__ nid, int* __restrict__ li_arr,
    int* __restrict__ cnt, int* __restrict__ done)
{
    int b = blockIdx.x * 256 + threadIdx.x;
    if (b < BB) atomicMax(&last_idx[sources[b]], b);
    __threadfence();
    __syncthreads();
    __shared__ int lastBlk;
    if (threadIdx.x == 0)
        lastBlk = (atomicAdd(done, 1) == (int)gridDim.x - 1);
    __syncthreads();
    if (lastBlk) {
        for (int n = threadIdx.x; n < N_NODES; n += 256) {
            int li = last_idx[n];
            if (li >= 0) { int p = atomicAdd(cnt, 1); nid[p] = n; li_arr[p] = li; }
        }
    }
}

// ---------------- GEMM 1 fused (compacted rows): BM=16, 768 thr (11 MFMA waves x 16 cols) ----------------
#define LDA_R 712   // 704 + 8 pad halfs

__global__ __launch_bounds__(768) void gemm_rnn_fused(
    const f16* __restrict__ Wc, const float* __restrict__ bcomb,
    const int* __restrict__ nid, const int* __restrict__ li_arr, const int* __restrict__ cnt,
    const int* __restrict__ destinations, const int* __restrict__ edge_idxs,
    const float* __restrict__ timestamps, const float* __restrict__ last_updated,
    const float* __restrict__ node_mem, const float* __restrict__ edge_features,
    const float* __restrict__ tw, const float* __restrict__ tb,
    const float* __restrict__ tnf, f16* __restrict__ FEAT)
{
    const int c = *cnt;
    const int R0 = blockIdx.x * 16;
    if (R0 >= c) return;
    __shared__ f16 As[16 * LDA_R];
    __shared__ int s_n[16], s_dst[16], s_ei[16];
    __shared__ float s_dt[16];
    const int t = threadIdx.x;
    if (t < 16) {
        int i = R0 + t; if (i > c - 1) i = c - 1;
        int n = nid[i], li = li_arr[i];
        s_n[t] = n; s_dst[t] = destinations[li]; s_ei[t] = edge_idxs[li];
        s_dt[t] = timestamps[li] - last_updated[n];
    }
    __syncthreads();
    for (int idx = t; idx < 16 * 88; idx += 768) {
        int row = idx / 88, sub = idx - row * 88;
        int seg = sub / 22, cpos = sub - seg * 22, k0 = cpos * 8;
        f16x8 o;
        if (seg < 3) {
            int n = (seg == 0) ? s_n[row] : (seg == 1) ? s_dst[row] : s_ei[row];
            const float* src = ((seg < 2) ? node_mem : edge_features) + (size_t)n * D + k0;
            float4 lo = *(const float4*)src;
            float4 hi = (cpos < 21) ? *(const float4*)(src + 4) : make_float4(0.f, 0.f, 0.f, 0.f);
            o[0] = (f16)lo.x; o[1] = (f16)lo.y; o[2] = (f16)lo.z; o[3] = (f16)lo.w;
            o[4] = (f16)hi.x; o[5] = (f16)hi.y; o[6] = (f16)hi.z; o[7] = (f16)hi.w;
        } else {
            float dt = s_dt[row];
            #pragma unroll
            for (int j = 0; j < 8; ++j) {
                int kk = k0 + j;
                o[j] = (f16)((kk < D) ? __cosf(dt * tw[kk] + tb[kk]) : 0.f);
            }
        }
        *(f16x8*)(As + row * LDA_R + seg * 176 + k0) = o;
    }
    __syncthreads();
    const int w = t >> 6, l = t & 63;
    if (w >= 11) return;
    const int lane16 = l & 15, koff = (l >> 4) * 8;
    const int C0 = w * 16;
    const f16* Al = As + lane16 * LDA_R + koff;
    const f16* Bp = Wc + (size_t)(C0 + lane16) * 704 + koff;
    f32x4 acc = {};
    #pragma unroll 2
    for (int s = 0; s < 22; ++s) {
        f16x8 a = *(const f16x8*)(Al + s * 32);
        f16x8 b = *(const f16x8*)(Bp + s * 32);
        acc = __builtin_amdgcn_mfma_f32_16x16x32_f16(a, b, acc, 0, 0, 0);
    }
    const int col = C0 + lane16;
    const int rloc = (l >> 4) * 4;
    if (col < D) {
        const float bc = bcomb[col];
        #pragma unroll
        for (int reg = 0; reg < 4; ++reg) {
            int rl = rloc + reg;
            int r = R0 + rl;
            if (r >= c) continue;
            int n = s_n[rl];
            FEAT[(size_t)n * 176 + col] = (f16)(tanhf(acc[reg] + bc) + tnf[(size_t)n * D + col]);
        }
    }
}

// ---------------- embed_fused (BM=16): stage G + srcfeat -> lin1 -> lin2 -> mlp -> out ----------------
#define LDA_1 552   // G leading dim: 544 + 8
#define LDA_2 360   // Acat leading dim: 352 + 8
#define LDE  200    // Emb leading dim: 192 + 8

__global__ __launch_bounds__(768) void embed_fused(
    const f16* __restrict__ W1, const float* __restrict__ lin1_b,
    const f16* __restrict__ W2, const float* __restrict__ embc,
    const f16* __restrict__ Wm1, const float* __restrict__ b1,
    const float* __restrict__ w2, const float* __restrict__ b2,
    const float* __restrict__ w3, const float* __restrict__ b3,
    const f16* __restrict__ FEAT, const float* __restrict__ edge_features,
    const float* __restrict__ timestamps, const float* __restrict__ nbr_edge_times,
    const int* __restrict__ neighbors, const int* __restrict__ nbr_edge_idxs,
    const int* __restrict__ sources,
    const float* __restrict__ tw, const float* __restrict__ tb,
    float* __restrict__ out)
{
    __shared__ f16 As[16 * LDA_1];      // G staging; reused as Emb after lin1/lin2
    __shared__ f16 Acat[16 * LDA_2];    // [H1(0:176) | srcfeat(176:352)]
    __shared__ float sH[16][84];
    __shared__ float s_w2[10 * HIDD];
    __shared__ float s_b2[10], s_w3[10], s_b3;
    __shared__ int s_nbr[160], s_nei[160], s_src[16];
    __shared__ float s_net[160], s_ts[16];
    const int t = threadIdx.x;
    const int R0 = blockIdx.x * 16;
    for (int i = t; i < 10 * HIDD; i += 768) s_w2[i] = w2[i];
    if (t < 10) { s_b2[t] = b2[t]; s_w3[t] = w3[t]; }
    if (t == 10) s_b3 = b3[0];
    if (t >= 64 && t < 224) {
        int u = t - 64;
        s_nbr[u] = neighbors[R0 * KK + u];
    } else if (t >= 224 && t < 384) {
        int u = t - 224;
        s_nei[u] = nbr_edge_idxs[R0 * KK + u];
        s_net[u] = nbr_edge_times[R0 * KK + u];
    } else if (t >= 384 && t < 400) {
        s_ts[t - 384] = timestamps[R0 + t - 384];
    } else if (t >= 400 && t < 416) {
        s_src[t - 400] = sources[R0 + t - 400];
    }
    __syncthreads();
    for (int idx = t; idx < 16 * 90 + 16 * 22; idx += 768) {
        if (idx < 16 * 90) {
            int row = idx / 90, c = idx - row * 90;
            if (c < 22) {
                int k0 = c * 8;
                f16x8 v[KK];
                #pragma unroll
                for (int k = 0; k < KK; ++k)
                    v[k] = *(const f16x8*)(FEAT + (size_t)s_nbr[row * KK + k] * 176 + k0);
                float a[8] = {};
                #pragma unroll
                for (int k = 0; k < KK; ++k) {
                    #pragma unroll
                    for (int j = 0; j < 8; ++j) a[j] += (float)v[k][j];
                }
                f16x8 o;
                #pragma unroll
                for (int j = 0; j < 8; ++j) o[j] = (f16)a[j];
                *(f16x8*)(As + row * LDA_1 + k0) = o;
            } else if (c < 44) {
                int k0 = (c - 22) * 8;
                float ts = s_ts[row];
                f16x8 o;
                #pragma unroll
                for (int j = 0; j < 8; ++j) {
                    int kk = k0 + j;
                    float a = 0.f;
                    if (kk < D) {
                        float w = tw[kk], bb = tb[kk];
                        #pragma unroll
                        for (int k = 0; k < KK; ++k) a += __cosf((ts - s_net[row * KK + k]) * w + bb);
                    }
                    o[j] = (f16)a;
                }
                *(f16x8*)(As + row * LDA_1 + 176 + k0) = o;
            } else if (c < 88) {
                int cc = c - 44;
                f16x4 o;
                if (cc == 43) {
                    o[0] = o[1] = o[2] = o[3] = (f16)0.f;
                } else {
                    float4 e[KK];
                    #pragma unroll
                    for (int k = 0; k < KK; ++k)
                        e[k] = *(const float4*)(edge_features + (size_t)s_nei[row * KK + k] * D + cc * 4);
                    float a0 = 0.f, a1 = 0.f, a2 = 0.f, a3 = 0.f;
                    #pragma unroll
                    for (int k = 0; k < KK; ++k) { a0 += e[k].x; a1 += e[k].y; a2 += e[k].z; a3 += e[k].w; }
                    o[0] = (f16)a0; o[1] = (f16)a1; o[2] = (f16)a2; o[3] = (f16)a3;
                }
                *(f16x4*)(As + row * LDA_1 + 352 + cc * 4) = o;
            } else {
                f16x8 z = {};
                *(f16x8*)(As + row * LDA_1 + 528 + (c - 88) * 8) = z;
            }
        } else {
            int j = idx - 16 * 90;
            int row = j / 22, cc = j - row * 22;
            *(f16x8*)(Acat + row * LDA_2 + 176 + cc * 8) =
                *(const f16x8*)(FEAT + (size_t)s_src[row] * 176 + cc * 8);
        }
    }
    __syncthreads();
    const int w = t >> 6, l = t & 63;
    const int lane16 = l & 15, koff = (l >> 4) * 8;
    const int rloc = (l >> 4) * 4;
    const int C0 = w * 16;
    if (w < 11) {   // lin1 -> Acat[:,0:176)
        const f16* Al = As + lane16 * LDA_1 + koff;
        const f16* Bp = W1 + (size_t)(C0 + lane16) * 544 + koff;
        f32x4 acc = {};
        #pragma unroll 2
        for (int s = 0; s < 17; ++s) {
            f16x8 a = *(const f16x8*)(Al + s * 32);
            f16x8 b = *(const f16x8*)(Bp + s * 32);
            acc = __builtin_amdgcn_mfma_f32_16x16x32_f16(a, b, acc, 0, 0, 0);
        }
        const int col = C0 + lane16;
        if (col < 176) {
            const float bb = (col < D) ? 10.0f * lin1_b[col] : 0.f;
            #pragma unroll
            for (int reg = 0; reg < 4; ++reg) {
                int r = rloc + reg;
                Acat[r * LDA_2 + col] = (col < D) ? (f16)fmaxf(acc[reg] + bb, 0.f) : (f16)0.f;
            }
        }
    }
    __syncthreads();
    f16* Emb = As;   // reuse
    if (w < 11) {   // lin2 -> Emb
        const f16* Al = Acat + lane16 * LDA_2 + koff;
        const f16* Bp = W2 + (size_t)(C0 + lane16) * 352 + koff;
        f32x4 acc = {};
        #pragma unroll 2
        for (int s = 0; s < 11; ++s) {
            f16x8 a = *(const f16x8*)(Al + s * 32);
            f16x8 b = *(const f16x8*)(Bp + s * 32);
            acc = __builtin_amdgcn_mfma_f32_16x16x32_f16(a, b, acc, 0, 0, 0);
        }
        const int col = C0 + lane16;
        const float ec = (col < D) ? embc[col] : 0.f;
        #pragma unroll
        for (int reg = 0; reg < 4; ++reg) {
            int r = rloc + reg;
            Emb[r * LDE + col] = (col < D) ? (f16)(acc[reg] + ec) : (f16)0.f;
        }
    }
    __syncthreads();
    if (w < 5) {  // mlp layer 1 -> sH
        const int Cm = w * 16;
        const f16* Bp = Wm1 + (size_t)(Cm + lane16) * 192 + koff;
        const f16* Al = Emb + (lane16) * LDE + koff;
        f32x4 acc = {};
        #pragma unroll
        for (int s = 0; s < 6; ++s) {
            f16x8 a = *(const f16x8*)(Al + s * 32);
            f16x8 b = *(const f16x8*)(Bp + s * 32);
            acc = __builtin_amdgcn_mfma_f32_16x16x32_f16(a, b, acc, 0, 0, 0);
        }
        const int col = Cm + lane16;
        #pragma unroll
        for (int reg = 0; reg < 4; ++reg)
            sH[rloc + reg][col] = fmaxf(acc[reg] + b1[col], 0.f);
    }
    __syncthreads();
    if (t < 16) {
        float h2[10];
        #pragma unroll
        for (int j = 0; j < 10; ++j) h2[j] = s_b2[j];
        for (int f = 0; f < HIDD; ++f) {
            float hv = sH[t][f];
            #pragma unroll
            for (int j = 0; j < 10; ++j) h2[j] = fmaf(hv, s_w2[j * HIDD + f], h2[j]);
        }
        float logit = s_b3;
        #pragma unroll
        for (int j = 0; j < 10; ++j) logit += fmaxf(h2[j], 0.f) * s_w3[j];
        out[R0 + t] = 1.f / (1.f + expf(-logit));
    }
}

// ---------------- host ----------------

extern "C" void kernel_launch(void* const* d_in, const int* in_sizes, int n_in,
                              void* d_out, int out_size, void* d_ws, size_t ws_size,
                              hipStream_t stream) {
    const float* timestamps     = (const float*)d_in[0];
    const float* edge_features  = (const float*)d_in[1];
    const float* tnf            = (const float*)d_in[2];
    const float* node_mem       = (const float*)d_in[3];
    const float* last_updated   = (const float*)d_in[4];
    const float* nbr_edge_times = (const float*)d_in[5];
    const float* time_w         = (const float*)d_in[6];
    const float* time_b         = (const float*)d_in[7];
    const float* Wih            = (const float*)d_in[8];
    const float* Whh            = (const float*)d_in[9];
    const float* bih            = (const float*)d_in[10];
    const float* bhh            = (const float*)d_in[11];
    const float* lin1_w         = (const float*)d_in[12];
    const float* lin1_b         = (const float*)d_in[13];
    const float* lin2_w         = (const float*)d_in[14];
    const float* lin2_b         = (const float*)d_in[15];
    const float* w1             = (const float*)d_in[16];
    const float* b1             = (const float*)d_in[17];
    const float* w2             = (const float*)d_in[18];
    const float* b2             = (const float*)d_in[19];
    const float* w3             = (const float*)d_in[20];
    const float* b3             = (const float*)d_in[21];
    const int* sources          = (const int*)d_in[22];
    const int* destinations     = (const int*)d_in[23];
    const int* edge_idxs        = (const int*)d_in[24];
    const int* neighbors        = (const int*)d_in[25];
    const int* nbr_edge_idxs    = (const int*)d_in[26];
    float* out = (float*)d_out;

    char* p = (char*)d_ws;
    auto bump = [&p](size_t bytes) { char* r = p; p += (bytes + 255) & ~(size_t)255; return r; };
    int* last_idx = (int*)bump(N_NODES * 4);
    int* nid      = (int*)bump(N_NODES * 4);
    int* li_arr   = (int*)bump(N_NODES * 4);
    int* cnt      = (int*)bump(256);
    int* done     = (int*)bump(256);
    f16* Wc16     = (f16*)bump((size_t)192 * 704 * 2);
    f16* W1_16    = (f16*)bump((size_t)192 * 544 * 2);
    f16* W2_16    = (f16*)bump((size_t)192 * 352 * 2);
    f16* Wm1_16   = (f16*)bump((size_t)80 * 192 * 2);
    float* bcomb  = (float*)bump(D * 4);
    float* embc   = (float*)bump(D * 4);
    f16* FEAT16   = (f16*)bump((size_t)N_NODES * 176 * 2);

    hipLaunchKernelGGL(conv_weights, dim3((CR6 + 255) / 256), dim3(256), 0, stream,
                       Wih, Whh, lin1_w, lin2_w, w1, bih, bhh, lin2_b, time_b,
                       node_mem, tnf, Wc16, W1_16, W2_16, Wm1_16, bcomb, embc,
                       FEAT16, last_idx, cnt, done);

    hipLaunchKernelGGL(scatter_compact, dim3(BB / 256), dim3(256), 0, stream,
                       sources, last_idx, nid, li_arr, cnt, done);

    hipLaunchKernelGGL(gemm_rnn_fused, dim3((N_NODES + 15) / 16), dim3(768), 0, stream,
                       Wc16, bcomb, nid, li_arr, cnt, destinations, edge_idxs,
                       timestamps, last_updated, node_mem, edge_features,
                       time_w, time_b, tnf, FEAT16);

    hipLaunchKernelGGL(embed_fused, dim3(BB / 16), dim3(768), 0, stream,
                       W1_16, lin1_b, W2_16, embc, Wm1_16, b1, w2, b2, w3, b3,
                       FEAT16, edge_features, timestamps, nbr_edge_times,
                       neighbors, nbr_edge_idxs, sources, time_w, time_b, out);
}

// Round 18
// 90.581 us; speedup vs baseline: 1.7265x; 1.1965x over previous
//
#include <hip/hip_runtime.h>
#include <math.h>

#define N_NODES 10000
#define BB 8192
#define KK 10
#define D 172
#define HIDD 80

typedef _Float16 f16;
typedef f16 f16x8 __attribute__((ext_vector_type(8)));
typedef f16 f16x4 __attribute__((ext_vector_type(4)));
typedef float f32x4 __attribute__((ext_vector_type(4)));

// ---------------- index prep ----------------

__global__ void scatter_last(const int* __restrict__ sources, int* __restrict__ last_idx) {
    int b = blockIdx.x * blockDim.x + threadIdx.x;
    if (b < BB) atomicMax(&last_idx[sources[b]], b);
}

__global__ void compact_nodes(const int* __restrict__ last_idx, int* __restrict__ nid,
                              int* __restrict__ li_arr, int* __restrict__ cnt) {
    int n = blockIdx.x * blockDim.x + threadIdx.x;
    if (n < N_NODES) {
        int li = last_idx[n];
        if (li >= 0) { int p = atomicAdd(cnt, 1); nid[p] = n; li_arr[p] = li; }
    }
}

// ---------------- conv_weights: flat 1D, 7 ranges (weights, consts, FEAT, init) ----------------
#define CR0 135168              // Wc 192*704
#define CR1 (CR0 + 104448)      // W1 192*544
#define CR2 (CR1 + 67584)       // W2 192*352
#define CR3 (CR2 + 15360)       // Wm1 80*192
#define CR4 (CR3 + 192)         // bcomb/embc
#define CR5 (CR4 + 220000)      // FEAT 10000*22
#define CR6 (CR5 + 10001)       // last_idx init + cnt

__global__ __launch_bounds__(256) void conv_weights(
    const float* __restrict__ Wih, const float* __restrict__ Whh,
    const float* __restrict__ lin1_w, const float* __restrict__ lin2_w,
    const float* __restrict__ w1,
    const float* __restrict__ bih, const float* __restrict__ bhh,
    const float* __restrict__ lin2_b, const float* __restrict__ tb,
    const float* __restrict__ node_mem, const float* __restrict__ tnf,
    f16* __restrict__ Wc, f16* __restrict__ W1, f16* __restrict__ W2,
    f16* __restrict__ Wm1, float* __restrict__ bcomb, float* __restrict__ embc,
    f16* __restrict__ FEAT, int* __restrict__ last_idx, int* __restrict__ cnt)
{
    const int idx = blockIdx.x * 256 + threadIdx.x;
    if (idx < CR0) {
        int n = idx / 704, k = idx % 704, seg = k / 176, kk = k % 176;
        float v = 0.f;
        if (n < D && kk < D) {
            v = Wih[n * 688 + seg * D + kk];
            if (seg == 0) v += Whh[n * D + kk];
        }
        Wc[idx] = (f16)v;
    } else if (idx < CR1) {
        int i = idx - CR0;
        int n = i / 544, k = i % 544, seg = k / 176, kk = k % 176;
        float v = 0.f;
        if (n < D && seg < 3 && kk < D) v = lin1_w[n * 516 + seg * D + kk];
        W1[i] = (f16)v;
    } else if (idx < CR2) {
        int i = idx - CR1;
        int n = i / 352, k = i % 352, seg = k / 176, kk = k % 176;
        float v = 0.f;
        if (n < D && kk < D) v = lin2_w[n * 516 + seg * D + kk];
        W2[i] = (f16)v;
    } else if (idx < CR3) {
        int i = idx - CR2;
        int n = i / 192, k = i % 192;
        Wm1[i] = (f16)((k < D) ? w1[n * D + k] : 0.f);
    } else if (idx < CR4) {
        int i = idx - CR3;
        if (i < D) {
            bcomb[i] = bih[i] + bhh[i];
            float acc = lin2_b[i];
            for (int j = 0; j < D; ++j) acc += lin2_w[i * 516 + 344 + j] * __cosf(tb[j]);
            embc[i] = acc;
        }
    } else if (idx < CR5) {
        int i = idx - CR4;
        int n = i / 22, k0 = (i % 22) * 8;
        f16x8 o;
        #pragma unroll
        for (int j = 0; j < 8; ++j) {
            int kk = k0 + j;
            float v = (kk < D) ? node_mem[(size_t)n * D + kk] + tnf[(size_t)n * D + kk] : 0.f;
            o[j] = (f16)v;
        }
        *(f16x8*)(FEAT + (size_t)n * 176 + k0) = o;
    } else if (idx < CR6) {
        int i = idx - CR5;
        if (i < N_NODES) last_idx[i] = -1;
        else *cnt = 0;
    }
}

// ---------------- GEMM 1 fused: BM=16 rows, 768 thr (11 MFMA waves x 16 cols) ----------------
#define LDA_R 712   // 704 + 8 pad halfs

__global__ __launch_bounds__(768) void gemm_rnn_fused(
    const f16* __restrict__ Wc, const float* __restrict__ bcomb,
    const int* __restrict__ nid, const int* __restrict__ li_arr, const int* __restrict__ cnt,
    const int* __restrict__ destinations, const int* __restrict__ edge_idxs,
    const float* __restrict__ timestamps, const float* __restrict__ last_updated,
    const float* __restrict__ node_mem, const float* __restrict__ edge_features,
    const float* __restrict__ tw, const float* __restrict__ tb,
    const float* __restrict__ tnf, f16* __restrict__ FEAT)
{
    const int c = *cnt;
    const int R0 = blockIdx.x * 16;
    if (R0 >= c) return;
    __shared__ f16 As[16 * LDA_R];
    __shared__ int s_n[16], s_dst[16], s_ei[16];
    __shared__ float s_dt[16];
    const int t = threadIdx.x;
    if (t < 16) {
        int i = R0 + t; if (i > c - 1) i = c - 1;
        int n = nid[i], li = li_arr[i];
        s_n[t] = n; s_dst[t] = destinations[li]; s_ei[t] = edge_idxs[li];
        s_dt[t] = timestamps[li] - last_updated[n];
    }
    __syncthreads();
    for (int idx = t; idx < 16 * 88; idx += 768) {
        int row = idx / 88, sub = idx - row * 88;
        int seg = sub / 22, cpos = sub - seg * 22, k0 = cpos * 8;
        f16x8 o;
        if (seg < 3) {
            int n = (seg == 0) ? s_n[row] : (seg == 1) ? s_dst[row] : s_ei[row];
            const float* src = ((seg < 2) ? node_mem : edge_features) + (size_t)n * D + k0;
            float4 lo = *(const float4*)src;
            float4 hi = (cpos < 21) ? *(const float4*)(src + 4) : make_float4(0.f, 0.f, 0.f, 0.f);
            o[0] = (f16)lo.x; o[1] = (f16)lo.y; o[2] = (f16)lo.z; o[3] = (f16)lo.w;
            o[4] = (f16)hi.x; o[5] = (f16)hi.y; o[6] = (f16)hi.z; o[7] = (f16)hi.w;
        } else {
            float dt = s_dt[row];
            #pragma unroll
            for (int j = 0; j < 8; ++j) {
                int kk = k0 + j;
                o[j] = (f16)((kk < D) ? __cosf(dt * tw[kk] + tb[kk]) : 0.f);
            }
        }
        *(f16x8*)(As + row * LDA_R + seg * 176 + k0) = o;
    }
    __syncthreads();
    const int w = t >> 6, l = t & 63;
    if (w >= 11) return;
    const int lane16 = l & 15, koff = (l >> 4) * 8;
    const int C0 = w * 16;
    const f16* Al = As + lane16 * LDA_R + koff;
    const f16* Bp = Wc + (size_t)(C0 + lane16) * 704 + koff;
    f32x4 acc = {};
    #pragma unroll 2
    for (int s = 0; s < 22; ++s) {
        f16x8 a = *(const f16x8*)(Al + s * 32);
        f16x8 b = *(const f16x8*)(Bp + s * 32);
        acc = __builtin_amdgcn_mfma_f32_16x16x32_f16(a, b, acc, 0, 0, 0);
    }
    const int col = C0 + lane16;
    const int rloc = (l >> 4) * 4;
    if (col < D) {
        const float bc = bcomb[col];
        #pragma unroll
        for (int reg = 0; reg < 4; ++reg) {
            int rl = rloc + reg;
            int r = R0 + rl;
            if (r >= c) continue;
            int n = s_n[rl];
            FEAT[(size_t)n * 176 + col] = (f16)(tanhf(acc[reg] + bc) + tnf[(size_t)n * D + col]);
        }
    }
}

// ---------------- embed_fused (BM=16): stage G + srcfeat -> lin1 -> lin2 -> mlp -> out ----------------
#define LDA_1 552   // G leading dim: 544 + 8
#define LDA_2 360   // Acat leading dim: 352 + 8
#define LDE  200    // Emb leading dim: 192 + 8

__global__ __launch_bounds__(768) void embed_fused(
    const f16* __restrict__ W1, const float* __restrict__ lin1_b,
    const f16* __restrict__ W2, const float* __restrict__ embc,
    const f16* __restrict__ Wm1, const float* __restrict__ b1,
    const float* __restrict__ w2, const float* __restrict__ b2,
    const float* __restrict__ w3, const float* __restrict__ b3,
    const f16* __restrict__ FEAT, const float* __restrict__ edge_features,
    const float* __restrict__ timestamps, const float* __restrict__ nbr_edge_times,
    const int* __restrict__ neighbors, const int* __restrict__ nbr_edge_idxs,
    const int* __restrict__ sources,
    const float* __restrict__ tw, const float* __restrict__ tb,
    float* __restrict__ out)
{
    __shared__ f16 As[16 * LDA_1];      // G staging; reused as Emb after lin1/lin2
    __shared__ f16 Acat[16 * LDA_2];    // [H1(0:176) | srcfeat(176:352)]
    __shared__ float sH[16][84];
    __shared__ float s_w2[10 * HIDD];
    __shared__ float s_b2[10], s_w3[10], s_b3;
    __shared__ int s_nbr[160], s_nei[160], s_src[16];
    __shared__ float s_net[160], s_ts[16];
    const int t = threadIdx.x;
    const int R0 = blockIdx.x * 16;
    for (int i = t; i < 10 * HIDD; i += 768) s_w2[i] = w2[i];
    if (t < 10) { s_b2[t] = b2[t]; s_w3[t] = w3[t]; }
    if (t == 10) s_b3 = b3[0];
    if (t >= 64 && t < 224) {
        int u = t - 64;
        s_nbr[u] = neighbors[R0 * KK + u];
    } else if (t >= 224 && t < 384) {
        int u = t - 224;
        s_nei[u] = nbr_edge_idxs[R0 * KK + u];
        s_net[u] = nbr_edge_times[R0 * KK + u];
    } else if (t >= 384 && t < 400) {
        s_ts[t - 384] = timestamps[R0 + t - 384];
    } else if (t >= 400 && t < 416) {
        s_src[t - 400] = sources[R0 + t - 400];
    }
    __syncthreads();
    // stage: G rows (90 chunks) + srcfeat (22 chunks) per row; 16*112 = 1792 items
    for (int idx = t; idx < 16 * 90 + 16 * 22; idx += 768) {
        if (idx < 16 * 90) {
            int row = idx / 90, c = idx - row * 90;
            if (c < 22) {
                int k0 = c * 8;
                f16x8 v[KK];
                #pragma unroll
                for (int k = 0; k < KK; ++k)
                    v[k] = *(const f16x8*)(FEAT + (size_t)s_nbr[row * KK + k] * 176 + k0);
                float a[8] = {};
                #pragma unroll
                for (int k = 0; k < KK; ++k) {
                    #pragma unroll
                    for (int j = 0; j < 8; ++j) a[j] += (float)v[k][j];
                }
                f16x8 o;
                #pragma unroll
                for (int j = 0; j < 8; ++j) o[j] = (f16)a[j];
                *(f16x8*)(As + row * LDA_1 + k0) = o;
            } else if (c < 44) {
                int k0 = (c - 22) * 8;
                float ts = s_ts[row];
                f16x8 o;
                #pragma unroll
                for (int j = 0; j < 8; ++j) {
                    int kk = k0 + j;
                    float a = 0.f;
                    if (kk < D) {
                        float w = tw[kk], bb = tb[kk];
                        #pragma unroll
                        for (int k = 0; k < KK; ++k) a += __cosf((ts - s_net[row * KK + k]) * w + bb);
                    }
                    o[j] = (f16)a;
                }
                *(f16x8*)(As + row * LDA_1 + 176 + k0) = o;
            } else if (c < 88) {
                int cc = c - 44;
                f16x4 o;
                if (cc == 43) {
                    o[0] = o[1] = o[2] = o[3] = (f16)0.f;
                } else {
                    float4 e[KK];
                    #pragma unroll
                    for (int k = 0; k < KK; ++k)
                        e[k] = *(const float4*)(edge_features + (size_t)s_nei[row * KK + k] * D + cc * 4);
                    float a0 = 0.f, a1 = 0.f, a2 = 0.f, a3 = 0.f;
                    #pragma unroll
                    for (int k = 0; k < KK; ++k) { a0 += e[k].x; a1 += e[k].y; a2 += e[k].z; a3 += e[k].w; }
                    o[0] = (f16)a0; o[1] = (f16)a1; o[2] = (f16)a2; o[3] = (f16)a3;
                }
                *(f16x4*)(As + row * LDA_1 + 352 + cc * 4) = o;
            } else {
                f16x8 z = {};
                *(f16x8*)(As + row * LDA_1 + 528 + (c - 88) * 8) = z;
            }
        } else {
            int j = idx - 16 * 90;
            int row = j / 22, cc = j - row * 22;
            *(f16x8*)(Acat + row * LDA_2 + 176 + cc * 8) =
                *(const f16x8*)(FEAT + (size_t)s_src[row] * 176 + cc * 8);
        }
    }
    __syncthreads();
    const int w = t >> 6, l = t & 63;
    const int lane16 = l & 15, koff = (l >> 4) * 8;
    const int rloc = (l >> 4) * 4;
    const int C0 = w * 16;
    if (w < 11) {   // lin1: 11 waves x 16 cols, A from As (LDS), write H1 -> Acat[:,0:176)
        const f16* Al = As + lane16 * LDA_1 + koff;
        const f16* Bp = W1 + (size_t)(C0 + lane16) * 544 + koff;
        f32x4 acc = {};
        #pragma unroll 2
        for (int s = 0; s < 17; ++s) {
            f16x8 a = *(const f16x8*)(Al + s * 32);
            f16x8 b = *(const f16x8*)(Bp + s * 32);
            acc = __builtin_amdgcn_mfma_f32_16x16x32_f16(a, b, acc, 0, 0, 0);
        }
        const int col = C0 + lane16;
        if (col < 176) {
            const float bb = (col < D) ? 10.0f * lin1_b[col] : 0.f;
            #pragma unroll
            for (int reg = 0; reg < 4; ++reg) {
                int r = rloc + reg;
                Acat[r * LDA_2 + col] = (col < D) ? (f16)fmaxf(acc[reg] + bb, 0.f) : (f16)0.f;
            }
        }
    }
    __syncthreads();
    f16* Emb = As;   // reuse
    if (w < 11) {   // lin2: 11 waves x 16 cols, A from Acat (LDS), write Emb
        const f16* Al = Acat + lane16 * LDA_2 + koff;
        const f16* Bp = W2 + (size_t)(C0 + lane16) * 352 + koff;
        f32x4 acc = {};
        #pragma unroll 2
        for (int s = 0; s < 11; ++s) {
            f16x8 a = *(const f16x8*)(Al + s * 32);
            f16x8 b = *(const f16x8*)(Bp + s * 32);
            acc = __builtin_amdgcn_mfma_f32_16x16x32_f16(a, b, acc, 0, 0, 0);
        }
        const int col = C0 + lane16;
        const float ec = (col < D) ? embc[col] : 0.f;
        #pragma unroll
        for (int reg = 0; reg < 4; ++reg) {
            int r = rloc + reg;
            Emb[r * LDE + col] = (col < D) ? (f16)(acc[reg] + ec) : (f16)0.f;
        }
    }
    __syncthreads();
    if (w < 5) {  // mlp1: wave w -> cols w*16..+16
        const int Cm = w * 16;
        const f16* Bp = Wm1 + (size_t)(Cm + lane16) * 192 + koff;
        const f16* Al = Emb + (lane16) * LDE + koff;
        f32x4 acc = {};
        #pragma unroll
        for (int s = 0; s < 6; ++s) {
            f16x8 a = *(const f16x8*)(Al + s * 32);
            f16x8 b = *(const f16x8*)(Bp + s * 32);
            acc = __builtin_amdgcn_mfma_f32_16x16x32_f16(a, b, acc, 0, 0, 0);
        }
        const int col = Cm + lane16;
        #pragma unroll
        for (int reg = 0; reg < 4; ++reg)
            sH[rloc + reg][col] = fmaxf(acc[reg] + b1[col], 0.f);
    }
    __syncthreads();
    if (t < 16) {
        float h2[10];
        #pragma unroll
        for (int j = 0; j < 10; ++j) h2[j] = s_b2[j];
        for (int f = 0; f < HIDD; ++f) {
            float hv = sH[t][f];
            #pragma unroll
            for (int j = 0; j < 10; ++j) h2[j] = fmaf(hv, s_w2[j * HIDD + f], h2[j]);
        }
        float logit = s_b3;
        #pragma unroll
        for (int j = 0; j < 10; ++j) logit += fmaxf(h2[j], 0.f) * s_w3[j];
        out[R0 + t] = 1.f / (1.f + expf(-logit));
    }
}

// ---------------- host ----------------

extern "C" void kernel_launch(void* const* d_in, const int* in_sizes, int n_in,
                              void* d_out, int out_size, void* d_ws, size_t ws_size,
                              hipStream_t stream) {
    const float* timestamps     = (const float*)d_in[0];
    const float* edge_features  = (const float*)d_in[1];
    const float* tnf            = (const float*)d_in[2];
    const float* node_mem       = (const float*)d_in[3];
    const float* last_updated   = (const float*)d_in[4];
    const float* nbr_edge_times = (const float*)d_in[5];
    const float* time_w         = (const float*)d_in[6];
    const float* time_b         = (const float*)d_in[7];
    const float* Wih            = (const float*)d_in[8];
    const float* Whh            = (const float*)d_in[9];
    const float* bih            = (const float*)d_in[10];
    const float* bhh            = (const float*)d_in[11];
    const float* lin1_w         = (const float*)d_in[12];
    const float* lin1_b         = (const float*)d_in[13];
    const float* lin2_w         = (const float*)d_in[14];
    const float* lin2_b         = (const float*)d_in[15];
    const float* w1             = (const float*)d_in[16];
    const float* b1             = (const float*)d_in[17];
    const float* w2             = (const float*)d_in[18];
    const float* b2             = (const float*)d_in[19];
    const float* w3             = (const float*)d_in[20];
    const float* b3             = (const float*)d_in[21];
    const int* sources          = (const int*)d_in[22];
    const int* destinations     = (const int*)d_in[23];
    const int* edge_idxs        = (const int*)d_in[24];
    const int* neighbors        = (const int*)d_in[25];
    const int* nbr_edge_idxs    = (const int*)d_in[26];
    float* out = (float*)d_out;

    char* p = (char*)d_ws;
    auto bump = [&p](size_t bytes) { char* r = p; p += (bytes + 255) & ~(size_t)255; return r; };
    int* last_idx = (int*)bump(N_NODES * 4);
    int* nid      = (int*)bump(N_NODES * 4);
    int* li_arr   = (int*)bump(N_NODES * 4);
    int* cnt      = (int*)bump(256);
    f16* Wc16     = (f16*)bump((size_t)192 * 704 * 2);
    f16* W1_16    = (f16*)bump((size_t)192 * 544 * 2);
    f16* W2_16    = (f16*)bump((size_t)192 * 352 * 2);
    f16* Wm1_16   = (f16*)bump((size_t)80 * 192 * 2);
    float* bcomb  = (float*)bump(D * 4);
    float* embc   = (float*)bump(D * 4);
    f16* FEAT16   = (f16*)bump((size_t)N_NODES * 176 * 2);

    hipLaunchKernelGGL(conv_weights, dim3((CR6 + 255) / 256), dim3(256), 0, stream,
                       Wih, Whh, lin1_w, lin2_w, w1, bih, bhh, lin2_b, time_b,
                       node_mem, tnf, Wc16, W1_16, W2_16, Wm1_16, bcomb, embc,
                       FEAT16, last_idx, cnt);

    hipLaunchKernelGGL(scatter_last, dim3(BB / 256), dim3(256), 0, stream, sources, last_idx);
    hipLaunchKernelGGL(compact_nodes, dim3((N_NODES + 255) / 256), dim3(256), 0, stream,
                       last_idx, nid, li_arr, cnt);

    hipLaunchKernelGGL(gemm_rnn_fused, dim3((N_NODES + 15) / 16), dim3(768), 0, stream,
                       Wc16, bcomb, nid, li_arr, cnt, destinations, edge_idxs,
                       timestamps, last_updated, node_mem, edge_features,
                       time_w, time_b, tnf, FEAT16);

    hipLaunchKernelGGL(embed_fused, dim3(BB / 16), dim3(768), 0, stream,
                       W1_16, lin1_b, W2_16, embc, Wm1_16, b1, w2, b2, w3, b3,
                       FEAT16, edge_features, timestamps, nbr_edge_times,
                       neighbors, nbr_edge_idxs, sources, time_w, time_b, out);
}